// Round 5
// baseline (392.287 us; speedup 1.0000x reference)
//
#include <hip/hip_runtime.h>
#include <stdint.h>

// hierarchical cluster assignment: L=6, N=64, Q0=64, C=256 (fixed by reference setup)
#define NSLICE 384
#define QMAX   64
#define CDIM   256
#define NTHR   512
#define NWAVE  8

// Wave64 sum via DPP (VALU-only). Result valid in lane 63. old=0+add -> masked lanes add 0.
// Identical tree to r2/r4 -> bit-identical sums -> identical merge trajectory.
__device__ __forceinline__ float dpp_sum64(float v) {
#define DPP_ADD(c) v += __int_as_float(__builtin_amdgcn_update_dpp(0, __float_as_int(v), c, 0xf, 0xf, true))
    DPP_ADD(0x111); // row_shr:1
    DPP_ADD(0x112); // row_shr:2
    DPP_ADD(0x114); // row_shr:4
    DPP_ADD(0x118); // row_shr:8
    DPP_ADD(0x142); // row_bcast:15
    DPP_ADD(0x143); // row_bcast:31
#undef DPP_ADD
    return v;
}

template<int CTRL>
__device__ __forceinline__ unsigned dpp_min_step(unsigned v) {
    unsigned o = (unsigned)__builtin_amdgcn_update_dpp((int)v, (int)v, CTRL, 0xf, 0xf, false);
    return v < o ? v : o;
}

// full-wave u32 min, broadcast to all lanes via readlane (pure VALU, no DS pipe)
__device__ __forceinline__ unsigned wave_min_bcast(unsigned v) {
    v = dpp_min_step<0x111>(v);
    v = dpp_min_step<0x112>(v);
    v = dpp_min_step<0x114>(v);
    v = dpp_min_step<0x118>(v);
    v = dpp_min_step<0x142>(v);
    v = dpp_min_step<0x143>(v);
    return (unsigned)__builtin_amdgcn_readlane((int)v, 63);
}

__launch_bounds__(NTHR, 4)
__global__ void hca_kernel(const float* __restrict__ in, float* __restrict__ out) {
    // cen 64x256 f32 = 64KB ; dist 64x64 f32 = 16KB (diag stores sq). Exactly 80KB
    // -> 2 blocks/CU. cen row 63 (1KB) is DEAD after the first merge -> holds the
    // double-buffered per-row argmin keys (2 x u64[64] = 1KB).
    __shared__ __align__(16) float cen[QMAX * CDIM];
    __shared__ __align__(16) float dist[QMAX * QMAX];
    unsigned long long* const keybuf0 = (unsigned long long*)(cen + 63 * CDIM);
    unsigned long long* const keybuf1 = keybuf0 + QMAX;

    const int tid  = threadIdx.x;
    const int lane = tid & 63;
    const int w    = tid >> 6;
    const int slice = blockIdx.x;
    const float* src = in + (size_t)slice * (QMAX * CDIM);
    float* dst = out + (size_t)slice * (2 * CDIM);

    // ---- load slice into LDS ----
    {
        const float4* s4 = (const float4*)src;
        float4* c4 = (float4*)cen;
        #pragma unroll
        for (int i = 0; i < (QMAX * CDIM / 4) / NTHR; ++i)
            c4[tid + i * NTHR] = s4[tid + i * NTHR];
    }
    __syncthreads();

    // ---- init: wave w owns rows {w, w+8, ..., w+56}, cached in registers ----
    float4 A[8];
    #pragma unroll
    for (int r = 0; r < 8; ++r)
        A[r] = ((const float4*)(cen + (w + 8 * r) * CDIM))[lane];

    #pragma unroll
    for (int r = 0; r < 8; ++r) {            // sq[q] -> diagonal
        float t = A[r].x * A[r].x;
        t = fmaf(A[r].y, A[r].y, t); t = fmaf(A[r].z, A[r].z, t); t = fmaf(A[r].w, A[r].w, t);
        float s = dpp_sum64(t);
        if (lane == 63) dist[(w + 8 * r) * QMAX + (w + 8 * r)] = s;
    }
    __syncthreads();

    float sqq[8];
    #pragma unroll
    for (int r = 0; r < 8; ++r) sqq[r] = dist[(w + 8 * r) * QMAX + (w + 8 * r)];
    for (int p = 1; p < QMAX; ++p) {         // off-diag: each B row read once, 8 dots
        const float4 b = ((const float4*)(cen + p * CDIM))[lane];
        const float sqp = dist[p * QMAX + p];
        #pragma unroll
        for (int r = 0; r < 8; ++r) {
            const int q = w + 8 * r;
            if (q < p) {
                float t = A[r].x * b.x;
                t = fmaf(A[r].y, b.y, t); t = fmaf(A[r].z, b.z, t); t = fmaf(A[r].w, b.w, t);
                float s = dpp_sum64(t);
                if (lane == 63) {
                    float d2 = sqq[r] + sqp - 2.0f * s;
                    float d  = sqrtf(fmaxf(d2, 0.0f));
                    dist[q * QMAX + p] = d;
                    dist[p * QMAX + q] = d;
                }
            }
        }
    }
    __syncthreads();

    // merge centers + move dist row/col Q-1 -> y (all bit-exact copies/ops)
    auto merge_phase = [&](int Q, int x, int y) {
        if (tid < CDIM) {
            const int c = tid;
            float ax = cen[x * CDIM + c];
            float ay = cen[y * CDIM + c];
            float lv = cen[(Q - 1) * CDIM + c];
            cen[x * CDIM + c] = (ax + ay) * 0.5f;
            if (y != Q - 1) cen[y * CDIM + c] = lv;
        }
        if (y != Q - 1) {
            if (tid == 0) dist[y * QMAX + y] = dist[(Q - 1) * QMAX + (Q - 1)];
            for (int p = tid; p < Q - 1; p += NTHR) {
                if (p != y) {
                    float v = dist[(Q - 1) * QMAX + p];
                    dist[y * QMAX + p] = v;
                    dist[p * QMAX + y] = v;
                }
            }
        }
    };

    // fresh row/col x vs survivors; fixed-trip unroll -> 8 pipelined dot chains
    auto freshrow = [&](int Q, int x) {
        const int nQ = Q - 1;
        const float4 a = ((const float4*)(cen + x * CDIM))[lane];
        float t = a.x * a.x; t = fmaf(a.y, a.y, t); t = fmaf(a.z, a.z, t); t = fmaf(a.w, a.w, t);
        const float sxx = dpp_sum64(t);          // identical bits in every wave
        if (w == 0 && lane == 63) dist[x * QMAX + x] = sxx;
        #pragma unroll
        for (int k = 0; k < 8; ++k) {
            const int p = w + 8 * k;             // wave-uniform guards
            if (p < nQ && p != x) {
                float sqp = dist[p * QMAX + p];
                const float4 b = ((const float4*)(cen + p * CDIM))[lane];
                float u = a.x * b.x; u = fmaf(a.y, b.y, u); u = fmaf(a.z, b.z, u); u = fmaf(a.w, b.w, u);
                float s = dpp_sum64(u);
                if (lane == 63) {
                    float d2 = sxx + sqp - 2.0f * s;
                    float d  = sqrtf(fmaxf(d2, 0.0f));
                    dist[x * QMAX + p] = d;
                    dist[p * QMAX + x] = d;
                }
            }
        }
    };

    // exact per-row argmin (min d, then min col) of live row r over cols < Qlive
    auto rescan_row = [&](int r, int Qlive, unsigned long long* kdst) {
        unsigned d = 0xFFFFFFFFu;
        if (lane < Qlive && lane != r) d = __float_as_uint(dist[r * QMAX + lane]);
        unsigned gd = wave_min_bcast(d);
        unsigned c  = (d == gd) ? (unsigned)lane : 0xFFFFFFFFu;
        unsigned gc = wave_min_bcast(c);
        if (lane == 0) kdst[r] = ((unsigned long long)gd << 6) | gc;
    };

    // ---- iter Q=64: full-scan argmin (keys not yet initialized) ----
    {
        unsigned bdb = 0xFFFFFFFFu, bidx = 0xFFFu;
        for (int i = 0; i < 16; ++i) {
            float4 dv = ((const float4*)dist)[i * 64 + lane];
            int base = i * 256 + lane * 4;
            #pragma unroll
            for (int e = 0; e < 4; ++e) {
                int idx = base + e;
                int r = idx >> 6, c = idx & 63;
                unsigned db = __float_as_uint((&dv.x)[e]);
                bool ok = (r != c);
                bool lt = ok & ((db < bdb) | ((db == bdb) & ((unsigned)idx < bidx)));
                bdb  = lt ? db : bdb;
                bidx = lt ? (unsigned)idx : bidx;
            }
        }
        unsigned gd   = wave_min_bcast(bdb);
        unsigned cand = (bdb == gd) ? bidx : 0xFFFFFFFFu;
        unsigned flat = wave_min_bcast(cand);
        const int x = (int)(flat >> 6), y = (int)(flat & 63);
        __syncthreads();                         // scans done before mutation
        merge_phase(QMAX, x, y);
        __syncthreads();
        freshrow(QMAX, x);
        __syncthreads();
        // one-time key init for the 63 live rows (cen row 63 now dead)
        #pragma unroll
        for (int k = 0; k < 8; ++k) {
            int r = w + 8 * k;
            if (r < 63) rescan_row(r, 63, keybuf0);
        }
        __syncthreads();
    }

    // ---- incremental iters Q=63..3 ----
    for (int Q = 63; Q > 2; --Q) {
        unsigned long long* const ksrc = ((63 - Q) & 1) ? keybuf1 : keybuf0;
        unsigned long long* const kdst = ((63 - Q) & 1) ? keybuf0 : keybuf1;

        // A: global argmin over row keys (all waves redundantly; no barrier needed
        // before B: B never touches the key buffers)
        unsigned long long kk = (lane < Q) ? ksrc[lane] : ~0ull;
        unsigned dv = (lane < Q) ? (unsigned)(kk >> 6) : 0xFFFFFFFFu;
        unsigned gd = wave_min_bcast(dv);
        unsigned ix = (dv == gd) ? (((unsigned)lane << 6) | (unsigned)(kk & 63)) : 0xFFFFFFFFu;
        unsigned flat = wave_min_bcast(ix);
        const int x = (int)(flat >> 6), y = (int)(flat & 63);   // x < y guaranteed

        // B
        merge_phase(Q, x, y);
        __syncthreads();
        // C
        freshrow(Q, x);
        __syncthreads();
        // D: key maintenance. Reads ksrc + fresh dist rows x,y; writes kdst.
        {
            const int r  = lane;
            const int Qn = Q - 1;
            const bool live = (r < Qn) && (r != x);
            bool needRescan = false;
            unsigned long long newk = ~0ull;
            if (live) {
                unsigned long long oldk = ksrc[(r == y) ? (Q - 1) : r];
                const int ac = (int)(oldk & 63);
                needRescan = (ac == x) || (ac == y);
                if (ac == Q - 1) oldk = ~0ull;   // resurrected via y-candidate (relabel)
                unsigned long long kx =
                    ((unsigned long long)__float_as_uint(dist[x * QMAX + r]) << 6) | (unsigned)x;
                newk = oldk < kx ? oldk : kx;
                if (y != Q - 1 && r != y) {
                    unsigned long long ky =
                        ((unsigned long long)__float_as_uint(dist[y * QMAX + r]) << 6) | (unsigned)y;
                    newk = newk < ky ? newk : ky;
                }
            }
            unsigned long long mask = __ballot(live && needRescan) | (1ull << x);
            if (w == 0 && live && !needRescan) kdst[r] = newk;
            int i = 0;
            unsigned long long m = mask;
            while (m) {                          // wave-uniform: identical mask everywhere
                int rr = __builtin_ctzll(m);
                m &= m - 1;
                if ((i & 7) == w) rescan_row(rr, Qn, kdst);
                ++i;
            }
        }
        __syncthreads();
    }

    // ---- final 2 centers ----
    for (int i = tid; i < 2 * CDIM; i += NTHR)
        dst[i] = cen[i];
}

extern "C" void kernel_launch(void* const* d_in, const int* in_sizes, int n_in,
                              void* d_out, int out_size, void* d_ws, size_t ws_size,
                              hipStream_t stream) {
    (void)in_sizes; (void)n_in; (void)d_ws; (void)ws_size; (void)out_size;
    const float* in = (const float*)d_in[0];
    float* out = (float*)d_out;
    hca_kernel<<<NSLICE, NTHR, 0, stream>>>(in, out);
}

// Round 6
// 217.940 us; speedup vs baseline: 1.8000x; 1.8000x over previous
//
#include <hip/hip_runtime.h>
#include <stdint.h>

// hierarchical cluster assignment: L=6, N=64, Q0=64, C=256 (fixed by reference setup)
#define NSLICE 384
#define QMAX   64
#define CDIM   256
#define NTHR   512

// XOR-swizzled dist indexing: row access (fixed r, c varies) conflict-free;
// col access (fixed c, r varies) -> (c^r)%32 permutes banks -> 2-way max (free).
// Diagonal (c==r) lands at physical column 0 (scalar/uniform access only).
#define SW(r,c) ((r)*QMAX + ((c)^(r)))

// Wave64 sum via DPP (VALU-only). Result valid in lane 63. old=0+add -> masked lanes add 0.
// Identical tree to r2/r4 -> bit-identical sums -> identical merge trajectory.
__device__ __forceinline__ float dpp_sum64(float v) {
#define DPP_ADD(c) v += __int_as_float(__builtin_amdgcn_update_dpp(0, __float_as_int(v), c, 0xf, 0xf, true))
    DPP_ADD(0x111); // row_shr:1
    DPP_ADD(0x112); // row_shr:2
    DPP_ADD(0x114); // row_shr:4
    DPP_ADD(0x118); // row_shr:8
    DPP_ADD(0x142); // row_bcast:15
    DPP_ADD(0x143); // row_bcast:31
#undef DPP_ADD
    return v;
}

template<int CTRL>
__device__ __forceinline__ unsigned dpp_min_step(unsigned v) {
    unsigned o = (unsigned)__builtin_amdgcn_update_dpp((int)v, (int)v, CTRL, 0xf, 0xf, false);
    return v < o ? v : o;
}

// full-wave u32 min, broadcast to all lanes via readlane (pure VALU, no DS pipe)
__device__ __forceinline__ unsigned wave_min_bcast(unsigned v) {
    v = dpp_min_step<0x111>(v);
    v = dpp_min_step<0x112>(v);
    v = dpp_min_step<0x114>(v);
    v = dpp_min_step<0x118>(v);
    v = dpp_min_step<0x142>(v);
    v = dpp_min_step<0x143>(v);
    return (unsigned)__builtin_amdgcn_readlane((int)v, 63);
}

// min over groups of 8 lanes where the 8-value pattern repeats every 8 lanes
__device__ __forceinline__ unsigned oct_min_all(unsigned v) {
    v = dpp_min_step<0xB1>(v);   // quad_perm [1,0,3,2]
    v = dpp_min_step<0x4E>(v);   // quad_perm [2,3,0,1]
    v = dpp_min_step<0x124>(v);  // row_ror:4
    return v;
}

__launch_bounds__(NTHR, 4)
__global__ void hca_kernel(const float* __restrict__ in, float* __restrict__ out) {
    // cen 64x256 f32 = 64KB ; dist 64x64 f32 = 16KB (swizzled; diag stores sq).
    // Exactly 80KB -> 2 blocks/CU. dist row 63 cols 0-15 = argmin scratch for Q<=63.
    __shared__ __align__(16) float cen[QMAX * CDIM];
    __shared__ __align__(16) float dist[QMAX * QMAX];
    unsigned long long* const scratch = (unsigned long long*)(dist + 63 * QMAX);

    const int tid  = threadIdx.x;
    const int lane = tid & 63;
    const int w    = tid >> 6;
    const int slice = blockIdx.x;
    const float* src = in + (size_t)slice * (QMAX * CDIM);
    float* dst = out + (size_t)slice * (2 * CDIM);

    // ---- load slice into LDS ----
    {
        const float4* s4 = (const float4*)src;
        float4* c4 = (float4*)cen;
        #pragma unroll
        for (int i = 0; i < (QMAX * CDIM / 4) / NTHR; ++i)
            c4[tid + i * NTHR] = s4[tid + i * NTHR];
    }
    __syncthreads();

    // ---- init: wave w owns rows {w, w+8, ..., w+56}, cached in registers ----
    {
        float4 A[8];
        #pragma unroll
        for (int r = 0; r < 8; ++r)
            A[r] = ((const float4*)(cen + (w + 8 * r) * CDIM))[lane];

        #pragma unroll
        for (int r = 0; r < 8; ++r) {        // sq[q] -> diag (phys col 0)
            float t = A[r].x * A[r].x;
            t = fmaf(A[r].y, A[r].y, t); t = fmaf(A[r].z, A[r].z, t); t = fmaf(A[r].w, A[r].w, t);
            float s = dpp_sum64(t);
            if (lane == 63) dist[(w + 8 * r) * QMAX] = s;
        }
        __syncthreads();

        float sqq[8];
        #pragma unroll
        for (int r = 0; r < 8; ++r) sqq[r] = dist[(w + 8 * r) * QMAX];
        for (int p = 1; p < QMAX; ++p) {     // off-diag: each B row read once, 8 dots
            const float4 b = ((const float4*)(cen + p * CDIM))[lane];
            const float sqp = dist[p * QMAX];
            #pragma unroll
            for (int r = 0; r < 8; ++r) {
                const int q = w + 8 * r;
                if (q < p) {
                    float t = A[r].x * b.x;
                    t = fmaf(A[r].y, b.y, t); t = fmaf(A[r].z, b.z, t); t = fmaf(A[r].w, b.w, t);
                    float s = dpp_sum64(t);
                    if (lane == 63) {
                        float d2 = sqq[r] + sqp - 2.0f * s;
                        float d  = sqrtf(fmaxf(d2, 0.0f));
                        dist[SW(q, p)] = d;
                        dist[SW(p, q)] = d;
                    }
                }
            }
        }
    }
    __syncthreads();

    // ---- initial full scan (Q=64), all waves redundant, result kept in regs ----
    unsigned flat0;
    {
        unsigned bdb = 0xFFFFFFFFu, bidx = 0xFFFu;
        for (int i = 0; i < 16; ++i) {
            float4 dv = ((const float4*)dist)[i * 64 + lane];
            const int rr  = 4 * i + (lane >> 4);
            const int cc0 = (lane & 15) * 4;
            #pragma unroll
            for (int e = 0; e < 4; ++e) {
                int cc = cc0 + e;
                int c  = cc ^ rr;                       // logical column
                unsigned db = __float_as_uint((&dv.x)[e]);
                unsigned idx = (unsigned)(rr * 64 + c);
                bool ok = (cc != 0);                    // cc==0 <=> diagonal (holds sq)
                bool lt = ok & ((db < bdb) | ((db == bdb) & (idx < bidx)));
                bdb  = lt ? db : bdb;
                bidx = lt ? idx : bidx;
            }
        }
        unsigned gd   = wave_min_bcast(bdb);
        unsigned cand = (bdb == gd) ? bidx : 0xFFFFFFFFu;
        flat0 = wave_min_bcast(cand);
    }
    __syncthreads();                                    // scans done before P1 mutates

    // ---- 62 merge steps, 2 barriers each ----
    for (int Q = QMAX; Q > 2; --Q) {
        // ===== P1: combine -> (x,y); moves; fresh row/col x from register-merged row =====
        int x, y;
        if (Q == QMAX) {
            x = (int)(flat0 >> 6); y = (int)(flat0 & 63);
        } else {
            unsigned long long k = scratch[lane & 7];
            unsigned hi = (unsigned)(k >> 32), lo = (unsigned)k;
            unsigned ghi = oct_min_all(hi);
            unsigned c2  = (hi == ghi) ? lo : 0xFFFFFFFFu;
            unsigned flat = oct_min_all(c2);
            x = (int)(flat >> 6); y = (int)(flat & 63); // x < y guaranteed
        }

        // merged row in registers: bit-identical to reference's (cx+cy)*0.5
        const float4 cx = ((const float4*)(cen + x * CDIM))[lane];
        const float4 cy = ((const float4*)(cen + y * CDIM))[lane];
        float4 m;
        m.x = (cx.x + cy.x) * 0.5f; m.y = (cx.y + cy.y) * 0.5f;
        m.z = (cx.z + cy.z) * 0.5f; m.w = (cx.w + cy.w) * 0.5f;
        float t = m.x * m.x;
        t = fmaf(m.y, m.y, t); t = fmaf(m.z, m.z, t); t = fmaf(m.w, m.w, t);
        const float sxx = dpp_sum64(t);                 // identical bits in every wave
        if (w == 0 && lane == 63) dist[x * QMAX] = sxx; // diag x

        // dist row/col Q-1 -> y (bit-exact copies; swizzle => conflict-free both axes)
        if (y != Q - 1) {
            if (w == 6) {
                int c = lane;
                if (c < Q - 1 && c != x && c != y)
                    dist[SW(y, c)] = dist[SW(Q - 1, c)];
                if (lane == 63) dist[y * QMAX] = dist[(Q - 1) * QMAX];  // diag y <- diag Q-1
            }
            if (w == 7) {
                int r = lane;
                if (r < Q - 1 && r != x && r != y)
                    dist[SW(r, y)] = dist[SW(r, Q - 1)];
            }
        }

        // fresh row/col x vs survivors (p in NEW labels; p==y reads old row Q-1)
        #pragma unroll
        for (int k8 = 0; k8 < 8; ++k8) {
            const int p = w + 8 * k8;                   // wave-uniform
            if (p < Q - 1 && p != x) {
                const int p_old = (p == y) ? (Q - 1) : p;
                float sqp = dist[p_old * QMAX];         // diag (never diag y -> no race)
                const float4 b = ((const float4*)(cen + p_old * CDIM))[lane];
                float u = m.x * b.x;
                u = fmaf(m.y, b.y, u); u = fmaf(m.z, b.z, u); u = fmaf(m.w, b.w, u);
                float s = dpp_sum64(u);
                if (lane == 63) {
                    float d2 = sxx + sqp - 2.0f * s;
                    float d  = sqrtf(fmaxf(d2, 0.0f));
                    dist[SW(x, p)] = d;
                    dist[SW(p, x)] = d;
                }
            }
        }
        __syncthreads();

        // ===== P2: cen writeback (waves 0,1) overlapped with next scan (all waves) =====
        if (w == 0)
            ((float4*)(cen + x * CDIM))[lane] = m;
        if (w == 1 && y != Q - 1)
            ((float4*)(cen + y * CDIM))[lane] = ((const float4*)(cen + (Q - 1) * CDIM))[lane];

        if (Q > 3) {                                    // distributed scan for next iter
            const int Qs = Q - 1;
            unsigned bdb = 0xFFFFFFFFu, bidx = 0xFFFu;
            #pragma unroll
            for (int ii = 0; ii < 2; ++ii) {
                const int i = 2 * w + ii;
                if (4 * i < Qs) {                       // wave-uniform dead-row skip
                    float4 dv = ((const float4*)dist)[i * 64 + lane];
                    const int rr  = 4 * i + (lane >> 4);
                    const int cc0 = (lane & 15) * 4;
                    #pragma unroll
                    for (int e = 0; e < 4; ++e) {
                        int cc = cc0 + e;
                        int c  = cc ^ rr;
                        unsigned db = __float_as_uint((&dv.x)[e]);
                        unsigned idx = (unsigned)(rr * 64 + c);
                        bool ok = (rr < Qs) & (c < Qs) & (cc != 0);
                        bool lt = ok & ((db < bdb) | ((db == bdb) & (idx < bidx)));
                        bdb  = lt ? db : bdb;
                        bidx = lt ? idx : bidx;
                    }
                }
            }
            unsigned gd   = wave_min_bcast(bdb);
            unsigned cand = (bdb == gd) ? bidx : 0xFFFFFFFFu;
            unsigned gidx = wave_min_bcast(cand);
            if (lane == 0) scratch[w] = ((unsigned long long)gd << 32) | gidx;
        }
        __syncthreads();
    }

    // ---- final 2 centers ----
    for (int i = tid; i < 2 * CDIM; i += NTHR)
        dst[i] = cen[i];
}

extern "C" void kernel_launch(void* const* d_in, const int* in_sizes, int n_in,
                              void* d_out, int out_size, void* d_ws, size_t ws_size,
                              hipStream_t stream) {
    (void)in_sizes; (void)n_in; (void)d_ws; (void)ws_size; (void)out_size;
    const float* in = (const float*)d_in[0];
    float* out = (float*)d_out;
    hca_kernel<<<NSLICE, NTHR, 0, stream>>>(in, out);
}

// Round 7
// 136.005 us; speedup vs baseline: 2.8844x; 1.6024x over previous
//
#include <hip/hip_runtime.h>
#include <stdint.h>

// hierarchical cluster assignment: L=6, N=64, Q0=64, C=256 (fixed by reference setup)
#define NSLICE 384
#define QMAX   64
#define CDIM   256
#define NTHR   512

// XOR-swizzled dist indexing: row access conflict-free; col access permutes banks.
// Diagonal (c==r) lands at physical column 0 (init-only sq storage).
#define SW(r,c) ((r)*QMAX + ((c)^(r)))

// Wave64 sum via DPP (VALU-only). Result valid in lane 63. Identical tree to r2..r6
// -> bit-identical init distances -> same starting point.
__device__ __forceinline__ float dpp_sum64(float v) {
#define DPP_ADD(c) v += __int_as_float(__builtin_amdgcn_update_dpp(0, __float_as_int(v), c, 0xf, 0xf, true))
    DPP_ADD(0x111); // row_shr:1
    DPP_ADD(0x112); // row_shr:2
    DPP_ADD(0x114); // row_shr:4
    DPP_ADD(0x118); // row_shr:8
    DPP_ADD(0x142); // row_bcast:15
    DPP_ADD(0x143); // row_bcast:31
#undef DPP_ADD
    return v;
}

template<int CTRL>
__device__ __forceinline__ unsigned dpp_min_step(unsigned v) {
    unsigned o = (unsigned)__builtin_amdgcn_update_dpp((int)v, (int)v, CTRL, 0xf, 0xf, false);
    return v < o ? v : o;
}

__device__ __forceinline__ unsigned wave_min_bcast(unsigned v) {
    v = dpp_min_step<0x111>(v);
    v = dpp_min_step<0x112>(v);
    v = dpp_min_step<0x114>(v);
    v = dpp_min_step<0x118>(v);
    v = dpp_min_step<0x142>(v);
    v = dpp_min_step<0x143>(v);
    return (unsigned)__builtin_amdgcn_readlane((int)v, 63);
}

// min over groups of 8 lanes where the 8-value pattern repeats every 8 lanes
__device__ __forceinline__ unsigned oct_min_all(unsigned v) {
    v = dpp_min_step<0xB1>(v);   // quad_perm [1,0,3,2]
    v = dpp_min_step<0x4E>(v);   // quad_perm [2,3,0,1]
    v = dpp_min_step<0x124>(v);  // row_ror:4
    return v;
}

__launch_bounds__(NTHR, 4)
__global__ void hca_kernel(const float* __restrict__ in, float* __restrict__ out) {
    // cen 64x256 f32 = 64KB ; dist 64x64 f32 = 16KB (swizzled). Exactly 80KB
    // -> 2 blocks/CU. dist row 63 cols 0-15 = argmin scratch for Q<=63.
    __shared__ __align__(16) float cen[QMAX * CDIM];
    __shared__ __align__(16) float dist[QMAX * QMAX];
    unsigned long long* const scratch = (unsigned long long*)(dist + 63 * QMAX);

    const int tid  = threadIdx.x;
    const int lane = tid & 63;
    const int w    = tid >> 6;
    const int slice = blockIdx.x;
    const float* src = in + (size_t)slice * (QMAX * CDIM);
    float* dst = out + (size_t)slice * (2 * CDIM);

    // ---- load slice into LDS ----
    {
        const float4* s4 = (const float4*)src;
        float4* c4 = (float4*)cen;
        #pragma unroll
        for (int i = 0; i < (QMAX * CDIM / 4) / NTHR; ++i)
            c4[tid + i * NTHR] = s4[tid + i * NTHR];
    }
    __syncthreads();

    // ---- init gram: wave w owns rows {w, w+8, ..., w+56}, cached in registers ----
    {
        float4 A[8];
        #pragma unroll
        for (int r = 0; r < 8; ++r)
            A[r] = ((const float4*)(cen + (w + 8 * r) * CDIM))[lane];

        #pragma unroll
        for (int r = 0; r < 8; ++r) {        // sq[q] -> diag (phys col 0), init-only
            float t = A[r].x * A[r].x;
            t = fmaf(A[r].y, A[r].y, t); t = fmaf(A[r].z, A[r].z, t); t = fmaf(A[r].w, A[r].w, t);
            float s = dpp_sum64(t);
            if (lane == 63) dist[(w + 8 * r) * QMAX] = s;
        }
        __syncthreads();

        float sqq[8];
        #pragma unroll
        for (int r = 0; r < 8; ++r) sqq[r] = dist[(w + 8 * r) * QMAX];
        for (int p = 1; p < QMAX; ++p) {     // off-diag: each B row read once, 8 dots
            const float4 b = ((const float4*)(cen + p * CDIM))[lane];
            const float sqp = dist[p * QMAX];
            #pragma unroll
            for (int r = 0; r < 8; ++r) {
                const int q = w + 8 * r;
                if (q < p) {
                    float t = A[r].x * b.x;
                    t = fmaf(A[r].y, b.y, t); t = fmaf(A[r].z, b.z, t); t = fmaf(A[r].w, b.w, t);
                    float s = dpp_sum64(t);
                    if (lane == 63) {
                        float d2 = sqq[r] + sqp - 2.0f * s;
                        float d  = sqrtf(fmaxf(d2, 0.0f));
                        dist[SW(q, p)] = d;
                        dist[SW(p, q)] = d;
                    }
                }
            }
        }
    }
    __syncthreads();

    // ---- initial full scan (Q=64), all waves redundant, result kept in regs ----
    unsigned flat0, d0bits;
    {
        unsigned bdb = 0xFFFFFFFFu, bidx = 0xFFFu;
        for (int i = 0; i < 16; ++i) {
            float4 dv = ((const float4*)dist)[i * 64 + lane];
            const int rr  = 4 * i + (lane >> 4);
            const int cc0 = (lane & 15) * 4;
            #pragma unroll
            for (int e = 0; e < 4; ++e) {
                int cc = cc0 + e;
                int c  = cc ^ rr;                       // logical column
                unsigned db = __float_as_uint((&dv.x)[e]);
                unsigned idx = (unsigned)(rr * 64 + c);
                bool ok = (cc != 0);                    // cc==0 <=> diagonal (holds sq)
                bool lt = ok & ((db < bdb) | ((db == bdb) & (idx < bidx)));
                bdb  = lt ? db : bdb;
                bidx = lt ? idx : bidx;
            }
        }
        d0bits = wave_min_bcast(bdb);
        unsigned cand = (bdb == d0bits) ? bidx : 0xFFFFFFFFu;
        flat0 = wave_min_bcast(cand);
    }
    __syncthreads();                                    // scans done before P1 mutates

    // ---- 62 merge steps, 2 barriers each; Lance-Williams (WPGMC) distance update ----
    for (int Q = QMAX; Q > 2; --Q) {
        // ===== P1: combine -> (x,y,dxy); wave0: LW update + moves; wave1: cen =====
        int x, y; unsigned dxyb;
        if (Q == QMAX) {
            x = (int)(flat0 >> 6); y = (int)(flat0 & 63); dxyb = d0bits;
        } else {
            unsigned long long k = scratch[lane & 7];
            unsigned hi = (unsigned)(k >> 32), lo = (unsigned)k;
            unsigned ghi = oct_min_all(hi);
            unsigned c2  = (hi == ghi) ? lo : 0xFFFFFFFFu;
            unsigned flat = oct_min_all(c2);
            x = (int)(flat >> 6); y = (int)(flat & 63); // x < y guaranteed
            dxyb = ghi;
        }

        if (w == 0) {
            // d(m,p)^2 = 0.5*d(x,p)^2 + 0.5*d(y,p)^2 - 0.25*d(x,y)^2  (exact for midpoint)
            const int p = lane;
            const bool act = (p < Q - 1) && (p != x);
            const int p_old = (p == y) ? (Q - 1) : p;   // new label y = old row Q-1
            float dxp = 0.0f, dyp = 0.0f;
            if (act) {
                dxp = dist[SW(x, p_old)];               // old row x (read before write)
                dyp = dist[SW(y, p_old)];               // old row y (read before write)
            }
            const bool mv = (y != Q - 1) && (lane < Q - 1) && (lane != x) && (lane != y);
            float rowQ1 = 0.0f, colQ1 = 0.0f;
            if (mv) {
                rowQ1 = dist[SW(Q - 1, lane)];
                colQ1 = dist[SW(lane, Q - 1)];
            }
            const float dxy = __uint_as_float(dxyb);
            float t = 0.5f * (dxp * dxp + dyp * dyp) - 0.25f * (dxy * dxy);
            float d = sqrtf(fmaxf(t, 0.0f));
            if (mv) {                                   // relabel Q-1 -> y
                dist[SW(y, lane)] = rowQ1;
                dist[SW(lane, y)] = colQ1;
            }
            if (act) {                                  // fresh row/col x
                dist[SW(x, p)] = d;
                dist[SW(p, x)] = d;
            }
        }
        if (w == 1) {
            // all remaining center math: bit-identical to reference's (cx+cy)*0.5 + copy
            const float4 cx = ((const float4*)(cen + x * CDIM))[lane];
            const float4 cy = ((const float4*)(cen + y * CDIM))[lane];
            const float4 cq = ((const float4*)(cen + (Q - 1) * CDIM))[lane];
            float4 m;
            m.x = (cx.x + cy.x) * 0.5f; m.y = (cx.y + cy.y) * 0.5f;
            m.z = (cx.z + cy.z) * 0.5f; m.w = (cx.w + cy.w) * 0.5f;
            ((float4*)(cen + x * CDIM))[lane] = m;
            if (y != Q - 1)
                ((float4*)(cen + y * CDIM))[lane] = cq;
        }
        __syncthreads();

        // ===== P2: distributed scan for next iter (all 8 waves) =====
        if (Q > 3) {
            const int Qs = Q - 1;
            unsigned bdb = 0xFFFFFFFFu, bidx = 0xFFFu;
            #pragma unroll
            for (int ii = 0; ii < 2; ++ii) {
                const int i = 2 * w + ii;
                if (4 * i < Qs) {                       // wave-uniform dead-row skip
                    float4 dv = ((const float4*)dist)[i * 64 + lane];
                    const int rr  = 4 * i + (lane >> 4);
                    const int cc0 = (lane & 15) * 4;
                    #pragma unroll
                    for (int e = 0; e < 4; ++e) {
                        int cc = cc0 + e;
                        int c  = cc ^ rr;
                        unsigned db = __float_as_uint((&dv.x)[e]);
                        unsigned idx = (unsigned)(rr * 64 + c);
                        bool ok = (rr < Qs) & (c < Qs) & (cc != 0);
                        bool lt = ok & ((db < bdb) | ((db == bdb) & (idx < bidx)));
                        bdb  = lt ? db : bdb;
                        bidx = lt ? idx : bidx;
                    }
                }
            }
            unsigned gd   = wave_min_bcast(bdb);
            unsigned cand = (bdb == gd) ? bidx : 0xFFFFFFFFu;
            unsigned gidx = wave_min_bcast(cand);
            if (lane == 0) scratch[w] = ((unsigned long long)gd << 32) | gidx;
        }
        __syncthreads();
    }

    // ---- final 2 centers ----
    for (int i = tid; i < 2 * CDIM; i += NTHR)
        dst[i] = cen[i];
}

extern "C" void kernel_launch(void* const* d_in, const int* in_sizes, int n_in,
                              void* d_out, int out_size, void* d_ws, size_t ws_size,
                              hipStream_t stream) {
    (void)in_sizes; (void)n_in; (void)d_ws; (void)ws_size; (void)out_size;
    const float* in = (const float*)d_in[0];
    float* out = (float*)d_out;
    hca_kernel<<<NSLICE, NTHR, 0, stream>>>(in, out);
}